// Round 8
// baseline (349.621 us; speedup 1.0000x reference)
//
#include <hip/hip_runtime.h>
#include <hip/hip_bf16.h>
#include <stdint.h>

#define TLEN 64
#define BSZ 32
#define SLEN 64
#define HS 1024
#define VOC 32000
#define NROW (TLEN*BSZ)   // 2048
#define C_CONST_F 0.1712209f

// GEMM geometry: 256x256 tile, 8 waves, 4-slot K-pipeline, BK=32/slot (R3/R7-verified)
#define BM 256
#define BN 256
#define BKT 32
#define NKT (HS/BKT)          // 32 K-tiles
#define SLOT_BYTES 32768      // A 16KB + B 16KB
#define B_REGION 16384        // byte offset of B within slot

typedef __attribute__((ext_vector_type(8))) short short8;
typedef __attribute__((ext_vector_type(4))) float f32x4;

static __device__ __forceinline__ ushort f2bf(float f) {
    uint32_t u = __builtin_bit_cast(uint32_t, f);
    uint32_t r = (u + 0x7fffu + ((u >> 16) & 1u)) >> 16;
    return (ushort)r;
}
static __device__ __forceinline__ float bf2f(ushort u) {
    uint32_t v = ((uint32_t)u) << 16;
    return __builtin_bit_cast(float, v);
}
static __device__ __forceinline__ void async16(const void* g, void* lds) {
    __builtin_amdgcn_global_load_lds(
        (const __attribute__((address_space(1))) void*)g,
        (__attribute__((address_space(3))) void*)lds, 16, 0, 0);
}
static __device__ __forceinline__ int swz12(int e) { return e ^ (((e >> 4) & 15) << 1); }

// ---------------- MFMA copy-attention + fused gate ----------------------------------
// grid: 128 blocks = (b 0..31) x (tq 0..3). Block computes scores[16 t][64 s] for its
// (b, t-quarter) via split-bf16 MFMA (hi*hi + hi*lo + lo*hi; err ~|s|*2^-16), then
// masked softmax over s and p_c = attn * sigmoid(gate). K staged in 32-chunk LDS ring.
__global__ __launch_bounds__(256) void attn_kernel(const float* __restrict__ hidden,
                                                   const float* __restrict__ context,
                                                   const int* __restrict__ src,
                                                   const float* __restrict__ w_copy,
                                                   const float* __restrict__ b_copy,
                                                   float* __restrict__ cp,
                                                   float* __restrict__ p_c) {
    int b  = blockIdx.x >> 2;
    int tq = blockIdx.x & 3;
    int tid = threadIdx.x, wid = tid >> 6, lane = tid & 63;
    int lr = lane & 15, lg = lane >> 4;

    __shared__ float hb[3][16][36];
    __shared__ float cb[3][64][36];
    __shared__ float wb[3][32];
    __shared__ float sc[16][65];
    __shared__ float gred[16];
    __shared__ float cps[16];
    __shared__ int   sbuf[SLEN];

    if (tid < SLEN) sbuf[tid] = src[b * SLEN + tid];

    // per-thread load slots for one chunk
    const int cidx0 = tid * 2;            // c: 2 float4 per thread
    const int cs0 = cidx0 >> 3, ck0 = cidx0 & 7;
    const int cs1 = (cidx0 + 1) >> 3, ck1 = (cidx0 + 1) & 7;
    const float* cbase = context + (size_t)b * HS;            // + s*32*HS + k
    const float* hbase = hidden + ((size_t)(tq * 16) * 32 + b) * HS;  // + t*32*HS + k

    float4 rc0, rc1, rh, rw;
#define ALOAD(I)                                                                   \
    {                                                                              \
        rc0 = *(const float4*)(cbase + (size_t)cs0 * 32 * HS + (I) * 32 + ck0 * 4);\
        rc1 = *(const float4*)(cbase + (size_t)cs1 * 32 * HS + (I) * 32 + ck1 * 4);\
        if (tid < 128) rh = *(const float4*)(hbase + (size_t)(tid >> 3) * 32 * HS + (I) * 32 + (tid & 7) * 4); \
        if (tid < 8)  rw = *(const float4*)(w_copy + (I) * 32 + tid * 4);          \
    }
#define AWRITE(BUF)                                                                \
    {                                                                              \
        *(float4*)(&cb[BUF][cs0][ck0 * 4]) = rc0;                                  \
        *(float4*)(&cb[BUF][cs1][ck1 * 4]) = rc1;                                  \
        if (tid < 128) *(float4*)(&hb[BUF][tid >> 3][(tid & 7) * 4]) = rh;         \
        if (tid < 8)  *(float4*)(&wb[BUF][tid * 4]) = rw;                          \
    }

    f32x4 acc = f32x4{0.f, 0.f, 0.f, 0.f};
    float greg = 0.f;
    int gt = lane >> 2, gk = lane & 3;    // gate mapping (wave 0)

    // prologue: chunks 0,1 written; chunk 2 in regs
    ALOAD(0); AWRITE(0);
    ALOAD(1); AWRITE(1);
    ALOAD(2);
    __syncthreads();

    for (int i = 0; i < 32; ++i) {
        int buf = i % 3;
        // frags from LDS: A = h rows (shared), B = c rows for this wave's 16 s
        float4 a0 = *(const float4*)(&hb[buf][lr][lg * 8]);
        float4 a1 = *(const float4*)(&hb[buf][lr][lg * 8 + 4]);
        float4 b0 = *(const float4*)(&cb[buf][wid * 16 + lr][lg * 8]);
        float4 b1 = *(const float4*)(&cb[buf][wid * 16 + lr][lg * 8 + 4]);
        short8 ahi, alo, bhi, blo;
        float af[8] = {a0.x, a0.y, a0.z, a0.w, a1.x, a1.y, a1.z, a1.w};
        float bf[8] = {b0.x, b0.y, b0.z, b0.w, b1.x, b1.y, b1.z, b1.w};
        #pragma unroll
        for (int e = 0; e < 8; ++e) {
            uint32_t ua = __builtin_bit_cast(uint32_t, af[e]);
            ahi[e] = (short)(ua >> 16);
            alo[e] = (short)f2bf(af[e] - __builtin_bit_cast(float, ua & 0xffff0000u));
            uint32_t ub = __builtin_bit_cast(uint32_t, bf[e]);
            bhi[e] = (short)(ub >> 16);
            blo[e] = (short)f2bf(bf[e] - __builtin_bit_cast(float, ub & 0xffff0000u));
        }
        acc = __builtin_amdgcn_mfma_f32_16x16x32_bf16(ahi, bhi, acc, 0, 0, 0);
        acc = __builtin_amdgcn_mfma_f32_16x16x32_bf16(ahi, blo, acc, 0, 0, 0);
        acc = __builtin_amdgcn_mfma_f32_16x16x32_bf16(alo, bhi, acc, 0, 0, 0);
        if (wid == 0) {
            #pragma unroll
            for (int e = 0; e < 8; ++e)
                greg += hb[buf][gt][gk * 8 + e] * wb[buf][gk * 8 + e];
        }
        // stage ahead: write chunk i+2 (its buffer's readers finished at barrier end of i-1)
        if (i + 2 < 32) {
            AWRITE((i + 2) % 3);
            if (i + 3 < 32) ALOAD(i + 3);
        }
        __syncthreads();
    }
#undef ALOAD
#undef AWRITE

    // gate reduce (wave 0): sum over the 4 k-sublanes
    if (wid == 0) {
        greg += __shfl_xor(greg, 1, 64);
        greg += __shfl_xor(greg, 2, 64);
        if (gk == 0) gred[gt] = greg;
    }
    // scores to LDS: row t=(lg*4+r), col s=wid*16+lr
    #pragma unroll
    for (int r = 0; r < 4; ++r)
        sc[lg * 4 + r][wid * 16 + lr] = acc[r];
    __syncthreads();
    if (tid < 16) {
        float s = 1.f / (1.f + expf(-(gred[tid] + b_copy[0])));
        cps[tid] = s;
        cp[(size_t)(tq * 16 + tid) * 32 + b] = s;
    }
    __syncthreads();
    // softmax: thread (t = tid>>4, e = tid&15) handles s = e*4..e*4+3
    {
        int t = tid >> 4, e = tid & 15;
        float v[4];
        float mx = -INFINITY;
        #pragma unroll
        for (int i = 0; i < 4; ++i) {
            v[i] = sc[t][e * 4 + i];
            if (sbuf[e * 4 + i] == 0) v[i] = -INFINITY;
            mx = fmaxf(mx, v[i]);
        }
        for (int k = 8; k >= 1; k >>= 1) mx = fmaxf(mx, __shfl_xor(mx, k, 16));
        float se = 0.f;
        #pragma unroll
        for (int i = 0; i < 4; ++i) { v[i] = __expf(v[i] - mx); se += v[i]; }
        for (int k = 8; k >= 1; k >>= 1) se += __shfl_xor(se, k, 16);
        float g = cps[t] / se;
        int row = (tq * 16 + t) * 32 + b;
        float4 o; o.x = v[0] * g; o.y = v[1] * g; o.z = v[2] * g; o.w = v[3] * g;
        *(float4*)(p_c + (size_t)row * SLEN + e * 4) = o;
    }
}

// ---------------- f32 -> bf16 conversion (hidden + W_gen in one launch) -------------
__global__ __launch_bounds__(256) void cvt_kernel(const float* __restrict__ hidden,
                                                  const float* __restrict__ W_gen,
                                                  ushort* __restrict__ dst) {
    const int A4 = NROW * HS / 4;
    int i = blockIdx.x * 256 + threadIdx.x;
    float4 v = (i < A4) ? ((const float4*)hidden)[i] : ((const float4*)W_gen)[i - A4];
    ushort4 o;
    o.x = f2bf(v.x); o.y = f2bf(v.y); o.z = f2bf(v.z); o.w = f2bf(v.w);
    ((ushort4*)dst)[i] = o;
}

// ---------------- main GEMM (R7-verified, unchanged) --------------------------------
template <bool BF16L>
__global__ __launch_bounds__(512, 2) void gemm_kernel(const ushort* __restrict__ A,
                                                      const ushort* __restrict__ B,
                                                      const float* __restrict__ b_gen,
                                                      void* __restrict__ logits,
                                                      float* __restrict__ partials /*[NROW][500][2]*/) {
    __shared__ ushort sAB[4 * SLOT_BYTES / 2];    // 128 KB, 4 slots

    int orig = blockIdx.x;
    int wg = (orig & 7) * 125 + (orig >> 3);
    int mIdx = wg & 7;            // 8 m-tiles
    int nIdx = wg >> 3;           // 125 n-tiles
    int m0 = mIdx * BM, n0 = nIdx * BN;
    int tid = threadIdx.x, wid = tid >> 6, lane = tid & 63;
    int wm = (wid >> 2) * 128, wn = (wid & 3) * 64;
    int lr = lane & 15, lg = lane >> 4;

    const ushort* gA[2]; const ushort* gB[2];
    uint32_t ldsOffA[2], ldsOffB[2];
    #pragma unroll
    for (int j = 0; j < 2; ++j) {
        int s = j * 512 + tid;
        int row = s >> 2;
        int kc = (s & 3) ^ ((row >> 1) & 3);
        gA[j] = A + (size_t)(m0 + row) * HS + kc * 8;
        gB[j] = B + (size_t)(n0 + row) * HS + kc * 8;
        ldsOffA[j] = (uint32_t)((j * 512 + wid * 64) * 16);
        ldsOffB[j] = (uint32_t)(B_REGION + (j * 512 + wid * 64) * 16);
    }

    uint32_t kcs   = (uint32_t)((lg ^ ((lr >> 1) & 3)) * 16);
    uint32_t offAb = (uint32_t)(wm + lr) * 64 + kcs;
    uint32_t offBb = B_REGION + (uint32_t)(wn + lr) * 64 + kcs;

    f32x4 acc[8][4];
    #pragma unroll
    for (int m = 0; m < 8; ++m)
        #pragma unroll
        for (int n = 0; n < 4; ++n) acc[m][n] = f32x4{0.f, 0.f, 0.f, 0.f};

#define STAGE(KT)                                                          \
    {                                                                      \
        char* sd = (char*)sAB + ((KT) & 3) * SLOT_BYTES;                   \
        int k0s = (KT) * BKT;                                              \
        _Pragma("unroll")                                                  \
        for (int j = 0; j < 2; ++j) {                                      \
            async16(gA[j] + k0s, sd + ldsOffA[j]);                         \
            async16(gB[j] + k0s, sd + ldsOffB[j]);                         \
        }                                                                  \
    }

#define PHASE_BODY(KT, DOSTAGE)                                                        \
    {                                                                                  \
        const char* sl = (const char*)sAB + ((KT) & 3) * SLOT_BYTES;                   \
        short8 af[8], bv[4];                                                           \
        _Pragma("unroll")                                                              \
        for (int mb = 0; mb < 8; ++mb)                                                 \
            af[mb] = *(const short8*)(sl + offAb + mb * 1024);                         \
        _Pragma("unroll")                                                              \
        for (int nb = 0; nb < 4; ++nb)                                                 \
            bv[nb] = *(const short8*)(sl + offBb + nb * 1024);                         \
        if (DOSTAGE) STAGE((KT) + 3);                                                  \
        _Pragma("unroll")                                                              \
        for (int mb = 0; mb < 8; ++mb)                                                 \
            _Pragma("unroll")                                                          \
            for (int nb = 0; nb < 4; ++nb)                                             \
                acc[mb][nb] = __builtin_amdgcn_mfma_f32_16x16x32_bf16(af[mb], bv[nb],  \
                                                                     acc[mb][nb], 0, 0, 0); \
    }

#define GATE8 asm volatile("s_waitcnt vmcnt(8)\n\ts_barrier" ::: "memory")

    STAGE(0); STAGE(1); STAGE(2);

    for (int kb = 0; kb < 7; ++kb) {
        int kt = kb * 4;
        GATE8; PHASE_BODY(kt + 0, true);
        GATE8; PHASE_BODY(kt + 1, true);
        GATE8; PHASE_BODY(kt + 2, true);
        GATE8; PHASE_BODY(kt + 3, true);
    }
    GATE8; PHASE_BODY(28, true);
    GATE8; PHASE_BODY(29, false);
    asm volatile("s_waitcnt vmcnt(4)\n\ts_barrier" ::: "memory");
    PHASE_BODY(30, false);
    asm volatile("s_waitcnt vmcnt(0)\n\ts_barrier" ::: "memory");
    PHASE_BODY(31, false);
#undef PHASE_BODY
#undef STAGE
#undef GATE8

    asm volatile("s_barrier" ::: "memory");

    float bg[4];
    #pragma unroll
    for (int nb = 0; nb < 4; ++nb) bg[nb] = b_gen[n0 + wn + nb * 16 + lr];
    int chunk = nIdx * 4 + (wid & 3);
    ushort* stile = sAB + wid * 8192;

    #pragma unroll
    for (int mb = 0; mb < 8; ++mb) {
        #pragma unroll
        for (int r = 0; r < 4; ++r) {
            int rl = mb * 16 + lg * 4 + r;
            int row = m0 + wm + rl;
            float v[4];
            float mx = -INFINITY;
            #pragma unroll
            for (int nb = 0; nb < 4; ++nb) {
                v[nb] = acc[mb][nb][r] + bg[nb];
                mx = fmaxf(mx, v[nb]);
            }
            if (BF16L) {
                #pragma unroll
                for (int nb = 0; nb < 4; ++nb) {
                    int cl = nb * 16 + lr;
                    int slot_w = (cl >> 3) ^ (rl & 7);
                    stile[rl * 64 + slot_w * 8 + (cl & 7)] = f2bf(v[nb]);
                }
            } else {
                float* outp = (float*)logits;
                #pragma unroll
                for (int nb = 0; nb < 4; ++nb)
                    outp[(size_t)row * VOC + n0 + wn + nb * 16 + lr] = v[nb];
            }
            for (int k = 8; k >= 1; k >>= 1) mx = fmaxf(mx, __shfl_xor(mx, k, 16));
            float se = 0.f;
            #pragma unroll
            for (int nb = 0; nb < 4; ++nb) se += __expf(v[nb] - mx);
            for (int k = 8; k >= 1; k >>= 1) se += __shfl_xor(se, k, 16);
            if (lr == 0) {
                float2 pv; pv.x = mx; pv.y = se;
                *(float2*)(partials + ((size_t)row * 500 + chunk) * 2) = pv;
            }
        }
    }
    if (BF16L) {
        ushort* Lbf = (ushort*)logits;
        #pragma unroll
        for (int rep = 0; rep < 16; ++rep) {
            int idx = rep * 64 + lane;
            int rl = idx >> 3, c8 = idx & 7;
            int slot_r = c8 ^ (rl & 7);
            short8 val = *(const short8*)(stile + rl * 64 + slot_r * 8);
            ushort* dst = Lbf + (size_t)(m0 + wm + rl) * VOC + n0 + wn + c8 * 8;
            *(short8*)dst = val;
        }
    }
}

// ---------------- finalize: inline partial-reduce, softmax scale, scatter, log ------
template <bool BF16L>
__global__ __launch_bounds__(256) void finalize_kernel(const int* __restrict__ src,
                                                       const float* __restrict__ p_c,
                                                       const float* __restrict__ cp,
                                                       const float* __restrict__ partials,
                                                       const void* __restrict__ logits,
                                                       float* __restrict__ out) {
    int row = blockIdx.y;
    int c0 = blockIdx.x * 4096;
    int b = row & (BSZ - 1);
    __shared__ float addv[4096];
    __shared__ float MS[2];
    int tid = threadIdx.x;
    for (int i = tid; i < 4096; i += 256) addv[i] = 0.f;
    // wave 0: merge this row's 500 (max,sumexp) partials
    if (tid < 64) {
        float m = -INFINITY, s = 0.f;
        for (int c = tid; c < 500; c += 64) {
            float2 p = *(const float2*)(partials + ((size_t)row * 500 + c) * 2);
            float nm = fmaxf(m, p.x);
            s = s * __expf(m - nm) + p.y * __expf(p.x - nm);
            m = nm;
        }
        for (int k = 32; k >= 1; k >>= 1) {
            float om = __shfl_xor(m, k, 64), os = __shfl_xor(s, k, 64);
            float nm = fmaxf(m, om);
            s = s * __expf(m - nm) + os * __expf(om - nm);
            m = nm;
        }
        if (tid == 0) { MS[0] = m; MS[1] = s; }
    }
    __syncthreads();
    if (tid < SLEN) {
        int v = src[b * SLEN + tid];
        if (v >= c0 && v < c0 + 4096)
            atomicAdd(&addv[swz12(v - c0)], p_c[row * SLEN + tid]);
    }
    __syncthreads();
    int col = c0 + tid * 16;
    if (col >= VOC) return;
    float M = MS[0];
    float g = (1.f - cp[row]) / MS[1];
    float L[16];
    if (BF16L) {
        const ushort* lb = (const ushort*)logits + (size_t)row * VOC + col;
        short8 a = *(const short8*)lb;
        short8 c = *(const short8*)(lb + 8);
        for (int i = 0; i < 8; ++i) { L[i] = bf2f((ushort)a[i]); L[8 + i] = bf2f((ushort)c[i]); }
    } else {
        const float* lf = (const float*)logits + (size_t)row * VOC + col;
        for (int i = 0; i < 4; ++i) {
            float4 v = *(const float4*)(lf + i * 4);
            L[i * 4 + 0] = v.x; L[i * 4 + 1] = v.y; L[i * 4 + 2] = v.z; L[i * 4 + 3] = v.w;
        }
    }
    float res[16];
    for (int i = 0; i < 16; ++i) {
        float p = __expf(L[i] - M) * g + addv[swz12(tid * 16 + i)];
        res[i] = __logf(p) + C_CONST_F;
    }
    float* op = out + (size_t)row * VOC + col;
    for (int i = 0; i < 4; ++i) {
        float4 v;
        v.x = res[i * 4 + 0]; v.y = res[i * 4 + 1]; v.z = res[i * 4 + 2]; v.w = res[i * 4 + 3];
        *(float4*)(op + i * 4) = v;
    }
}

extern "C" void kernel_launch(void* const* d_in, const int* in_sizes, int n_in,
                              void* d_out, int out_size, void* d_ws, size_t ws_size,
                              hipStream_t stream) {
    const float* hidden  = (const float*)d_in[0];
    const float* context = (const float*)d_in[1];
    const int*   src     = (const int*)d_in[2];
    const float* W_gen   = (const float*)d_in[3];
    const float* b_gen   = (const float*)d_in[4];
    const float* w_copy  = (const float*)d_in[5];
    const float* b_copy  = (const float*)d_in[6];
    float* out = (float*)d_out;
    char* ws = (char*)d_ws;

    float*  cp       = (float*)(ws);                    // 8 KB
    float*  p_c      = (float*)(ws + 8192);             // 512 KB
    float*  partials = (float*)(ws + 548864);           // 8.192 MB
    ushort* Abf      = (ushort*)(ws + 8740864);         // 4 MB   (contiguous with Wbf)
    const size_t NEED_BF16 = 209543168;
    ushort* Lbf      = (ushort*)(ws + 78471168);        // 131 MB

    attn_kernel<<<BSZ * 4, 256, 0, stream>>>(hidden, context, src, w_copy, b_copy, cp, p_c);
    cvt_kernel<<<(NROW * HS / 4 + VOC * HS / 4) / 256, 256, 0, stream>>>(hidden, W_gen, Abf);

    int ggrid = (NROW / BM) * (VOC / BN);   // 8 * 125 = 1000
    dim3 fgrid(8, NROW);
    const ushort* Wb = (const ushort*)(ws + 12935168);
    if (ws_size >= NEED_BF16) {
        gemm_kernel<true><<<ggrid, 512, 0, stream>>>(Abf, Wb, b_gen, Lbf, partials);
        finalize_kernel<true><<<fgrid, 256, 0, stream>>>(src, p_c, cp, partials, Lbf, out);
    } else {
        gemm_kernel<false><<<ggrid, 512, 0, stream>>>(Abf, Wb, b_gen, out, partials);
        finalize_kernel<false><<<fgrid, 256, 0, stream>>>(src, p_c, cp, partials, out, out);
    }
}

// Round 9
// 334.455 us; speedup vs baseline: 1.0453x; 1.0453x over previous
//
#include <hip/hip_runtime.h>
#include <hip/hip_bf16.h>
#include <stdint.h>

#define TLEN 64
#define BSZ 32
#define SLEN 64
#define HS 1024
#define VOC 32000
#define NROW (TLEN*BSZ)   // 2048
#define C_CONST_F 0.1712209f

// GEMM geometry: 256x256 tile, 8 waves, 4-slot K-pipeline, BK=32/slot (R3/R7-verified)
#define BM 256
#define BN 256
#define BKT 32
#define NKT (HS/BKT)          // 32 K-tiles
#define SLOT_BYTES 32768      // A 16KB + B 16KB
#define B_REGION 16384        // byte offset of B within slot

typedef __attribute__((ext_vector_type(8))) short short8;
typedef __attribute__((ext_vector_type(4))) float f32x4;

static __device__ __forceinline__ ushort f2bf(float f) {
    uint32_t u = __builtin_bit_cast(uint32_t, f);
    uint32_t r = (u + 0x7fffu + ((u >> 16) & 1u)) >> 16;
    return (ushort)r;
}
static __device__ __forceinline__ float bf2f(ushort u) {
    uint32_t v = ((uint32_t)u) << 16;
    return __builtin_bit_cast(float, v);
}
static __device__ __forceinline__ void async16(const void* g, void* lds) {
    __builtin_amdgcn_global_load_lds(
        (const __attribute__((address_space(1))) void*)g,
        (__attribute__((address_space(3))) void*)lds, 16, 0, 0);
}
static __device__ __forceinline__ int swz12(int e) { return e ^ (((e >> 4) & 15) << 1); }

// ---------------- MFMA copy-attention + fused gate (R8 variant, under A/B) ----------
__global__ __launch_bounds__(256) void attn_kernel(const float* __restrict__ hidden,
                                                   const float* __restrict__ context,
                                                   const int* __restrict__ src,
                                                   const float* __restrict__ w_copy,
                                                   const float* __restrict__ b_copy,
                                                   float* __restrict__ cp,
                                                   float* __restrict__ p_c) {
    int b  = blockIdx.x >> 2;
    int tq = blockIdx.x & 3;
    int tid = threadIdx.x, wid = tid >> 6, lane = tid & 63;
    int lr = lane & 15, lg = lane >> 4;

    __shared__ float hb[3][16][36];
    __shared__ float cb[3][64][36];
    __shared__ float wb[3][32];
    __shared__ float sc[16][65];
    __shared__ float gred[16];
    __shared__ float cps[16];
    __shared__ int   sbuf[SLEN];

    if (tid < SLEN) sbuf[tid] = src[b * SLEN + tid];

    const int cidx0 = tid * 2;
    const int cs0 = cidx0 >> 3, ck0 = cidx0 & 7;
    const int cs1 = (cidx0 + 1) >> 3, ck1 = (cidx0 + 1) & 7;
    const float* cbase = context + (size_t)b * HS;
    const float* hbase = hidden + ((size_t)(tq * 16) * 32 + b) * HS;

    float4 rc0, rc1, rh, rw;
#define ALOAD(I)                                                                   \
    {                                                                              \
        rc0 = *(const float4*)(cbase + (size_t)cs0 * 32 * HS + (I) * 32 + ck0 * 4);\
        rc1 = *(const float4*)(cbase + (size_t)cs1 * 32 * HS + (I) * 32 + ck1 * 4);\
        if (tid < 128) rh = *(const float4*)(hbase + (size_t)(tid >> 3) * 32 * HS + (I) * 32 + (tid & 7) * 4); \
        if (tid < 8)  rw = *(const float4*)(w_copy + (I) * 32 + tid * 4);          \
    }
#define AWRITE(BUF)                                                                \
    {                                                                              \
        *(float4*)(&cb[BUF][cs0][ck0 * 4]) = rc0;                                  \
        *(float4*)(&cb[BUF][cs1][ck1 * 4]) = rc1;                                  \
        if (tid < 128) *(float4*)(&hb[BUF][tid >> 3][(tid & 7) * 4]) = rh;         \
        if (tid < 8)  *(float4*)(&wb[BUF][tid * 4]) = rw;                          \
    }

    f32x4 acc = f32x4{0.f, 0.f, 0.f, 0.f};
    float greg = 0.f;
    int gt = lane >> 2, gk = lane & 3;

    ALOAD(0); AWRITE(0);
    ALOAD(1); AWRITE(1);
    ALOAD(2);
    __syncthreads();

    for (int i = 0; i < 32; ++i) {
        int buf = i % 3;
        float4 a0 = *(const float4*)(&hb[buf][lr][lg * 8]);
        float4 a1 = *(const float4*)(&hb[buf][lr][lg * 8 + 4]);
        float4 b0 = *(const float4*)(&cb[buf][wid * 16 + lr][lg * 8]);
        float4 b1 = *(const float4*)(&cb[buf][wid * 16 + lr][lg * 8 + 4]);
        short8 ahi, alo, bhi, blo;
        float af[8] = {a0.x, a0.y, a0.z, a0.w, a1.x, a1.y, a1.z, a1.w};
        float bf[8] = {b0.x, b0.y, b0.z, b0.w, b1.x, b1.y, b1.z, b1.w};
        #pragma unroll
        for (int e = 0; e < 8; ++e) {
            uint32_t ua = __builtin_bit_cast(uint32_t, af[e]);
            ahi[e] = (short)(ua >> 16);
            alo[e] = (short)f2bf(af[e] - __builtin_bit_cast(float, ua & 0xffff0000u));
            uint32_t ub = __builtin_bit_cast(uint32_t, bf[e]);
            bhi[e] = (short)(ub >> 16);
            blo[e] = (short)f2bf(bf[e] - __builtin_bit_cast(float, ub & 0xffff0000u));
        }
        acc = __builtin_amdgcn_mfma_f32_16x16x32_bf16(ahi, bhi, acc, 0, 0, 0);
        acc = __builtin_amdgcn_mfma_f32_16x16x32_bf16(ahi, blo, acc, 0, 0, 0);
        acc = __builtin_amdgcn_mfma_f32_16x16x32_bf16(alo, bhi, acc, 0, 0, 0);
        if (wid == 0) {
            #pragma unroll
            for (int e = 0; e < 8; ++e)
                greg += hb[buf][gt][gk * 8 + e] * wb[buf][gk * 8 + e];
        }
        if (i + 2 < 32) {
            AWRITE((i + 2) % 3);
            if (i + 3 < 32) ALOAD(i + 3);
        }
        __syncthreads();
    }
#undef ALOAD
#undef AWRITE

    if (wid == 0) {
        greg += __shfl_xor(greg, 1, 64);
        greg += __shfl_xor(greg, 2, 64);
        if (gk == 0) gred[gt] = greg;
    }
    #pragma unroll
    for (int r = 0; r < 4; ++r)
        sc[lg * 4 + r][wid * 16 + lr] = acc[r];
    __syncthreads();
    if (tid < 16) {
        float s = 1.f / (1.f + expf(-(gred[tid] + b_copy[0])));
        cps[tid] = s;
        cp[(size_t)(tq * 16 + tid) * 32 + b] = s;
    }
    __syncthreads();
    {
        int t = tid >> 4, e = tid & 15;
        float v[4];
        float mx = -INFINITY;
        #pragma unroll
        for (int i = 0; i < 4; ++i) {
            v[i] = sc[t][e * 4 + i];
            if (sbuf[e * 4 + i] == 0) v[i] = -INFINITY;
            mx = fmaxf(mx, v[i]);
        }
        for (int k = 8; k >= 1; k >>= 1) mx = fmaxf(mx, __shfl_xor(mx, k, 16));
        float se = 0.f;
        #pragma unroll
        for (int i = 0; i < 4; ++i) { v[i] = __expf(v[i] - mx); se += v[i]; }
        for (int k = 8; k >= 1; k >>= 1) se += __shfl_xor(se, k, 16);
        float g = cps[t] / se;
        int row = (tq * 16 + t) * 32 + b;
        float4 o; o.x = v[0] * g; o.y = v[1] * g; o.z = v[2] * g; o.w = v[3] * g;
        *(float4*)(p_c + (size_t)row * SLEN + e * 4) = o;
    }
}

// ---------------- f32 -> bf16 conversion (hidden + W_gen in one launch) -------------
__global__ __launch_bounds__(256) void cvt_kernel(const float* __restrict__ hidden,
                                                  const float* __restrict__ W_gen,
                                                  ushort* __restrict__ dst) {
    const int A4 = NROW * HS / 4;
    int i = blockIdx.x * 256 + threadIdx.x;
    float4 v = (i < A4) ? ((const float4*)hidden)[i] : ((const float4*)W_gen)[i - A4];
    ushort4 o;
    o.x = f2bf(v.x); o.y = f2bf(v.y); o.z = f2bf(v.z); o.w = f2bf(v.w);
    ((ushort4*)dst)[i] = o;
}

// ---------------- main GEMM (R7-verified, unchanged) --------------------------------
template <bool BF16L>
__global__ __launch_bounds__(512, 2) void gemm_kernel(const ushort* __restrict__ A,
                                                      const ushort* __restrict__ B,
                                                      const float* __restrict__ b_gen,
                                                      void* __restrict__ logits,
                                                      float* __restrict__ partials /*[NROW][500][2]*/) {
    __shared__ ushort sAB[4 * SLOT_BYTES / 2];    // 128 KB, 4 slots

    int orig = blockIdx.x;
    int wg = (orig & 7) * 125 + (orig >> 3);
    int mIdx = wg & 7;            // 8 m-tiles
    int nIdx = wg >> 3;           // 125 n-tiles
    int m0 = mIdx * BM, n0 = nIdx * BN;
    int tid = threadIdx.x, wid = tid >> 6, lane = tid & 63;
    int wm = (wid >> 2) * 128, wn = (wid & 3) * 64;
    int lr = lane & 15, lg = lane >> 4;

    const ushort* gA[2]; const ushort* gB[2];
    uint32_t ldsOffA[2], ldsOffB[2];
    #pragma unroll
    for (int j = 0; j < 2; ++j) {
        int s = j * 512 + tid;
        int row = s >> 2;
        int kc = (s & 3) ^ ((row >> 1) & 3);
        gA[j] = A + (size_t)(m0 + row) * HS + kc * 8;
        gB[j] = B + (size_t)(n0 + row) * HS + kc * 8;
        ldsOffA[j] = (uint32_t)((j * 512 + wid * 64) * 16);
        ldsOffB[j] = (uint32_t)(B_REGION + (j * 512 + wid * 64) * 16);
    }

    uint32_t kcs   = (uint32_t)((lg ^ ((lr >> 1) & 3)) * 16);
    uint32_t offAb = (uint32_t)(wm + lr) * 64 + kcs;
    uint32_t offBb = B_REGION + (uint32_t)(wn + lr) * 64 + kcs;

    f32x4 acc[8][4];
    #pragma unroll
    for (int m = 0; m < 8; ++m)
        #pragma unroll
        for (int n = 0; n < 4; ++n) acc[m][n] = f32x4{0.f, 0.f, 0.f, 0.f};

#define STAGE(KT)                                                          \
    {                                                                      \
        char* sd = (char*)sAB + ((KT) & 3) * SLOT_BYTES;                   \
        int k0s = (KT) * BKT;                                              \
        _Pragma("unroll")                                                  \
        for (int j = 0; j < 2; ++j) {                                      \
            async16(gA[j] + k0s, sd + ldsOffA[j]);                         \
            async16(gB[j] + k0s, sd + ldsOffB[j]);                         \
        }                                                                  \
    }

#define PHASE_BODY(KT, DOSTAGE)                                                        \
    {                                                                                  \
        const char* sl = (const char*)sAB + ((KT) & 3) * SLOT_BYTES;                   \
        short8 af[8], bv[4];                                                           \
        _Pragma("unroll")                                                              \
        for (int mb = 0; mb < 8; ++mb)                                                 \
            af[mb] = *(const short8*)(sl + offAb + mb * 1024);                         \
        _Pragma("unroll")                                                              \
        for (int nb = 0; nb < 4; ++nb)                                                 \
            bv[nb] = *(const short8*)(sl + offBb + nb * 1024);                         \
        if (DOSTAGE) STAGE((KT) + 3);                                                  \
        _Pragma("unroll")                                                              \
        for (int mb = 0; mb < 8; ++mb)                                                 \
            _Pragma("unroll")                                                          \
            for (int nb = 0; nb < 4; ++nb)                                             \
                acc[mb][nb] = __builtin_amdgcn_mfma_f32_16x16x32_bf16(af[mb], bv[nb],  \
                                                                     acc[mb][nb], 0, 0, 0); \
    }

#define GATE8 asm volatile("s_waitcnt vmcnt(8)\n\ts_barrier" ::: "memory")

    STAGE(0); STAGE(1); STAGE(2);

    for (int kb = 0; kb < 7; ++kb) {
        int kt = kb * 4;
        GATE8; PHASE_BODY(kt + 0, true);
        GATE8; PHASE_BODY(kt + 1, true);
        GATE8; PHASE_BODY(kt + 2, true);
        GATE8; PHASE_BODY(kt + 3, true);
    }
    GATE8; PHASE_BODY(28, true);
    GATE8; PHASE_BODY(29, false);
    asm volatile("s_waitcnt vmcnt(4)\n\ts_barrier" ::: "memory");
    PHASE_BODY(30, false);
    asm volatile("s_waitcnt vmcnt(0)\n\ts_barrier" ::: "memory");
    PHASE_BODY(31, false);
#undef PHASE_BODY
#undef STAGE
#undef GATE8

    asm volatile("s_barrier" ::: "memory");

    float bg[4];
    #pragma unroll
    for (int nb = 0; nb < 4; ++nb) bg[nb] = b_gen[n0 + wn + nb * 16 + lr];
    int chunk = nIdx * 4 + (wid & 3);
    ushort* stile = sAB + wid * 8192;

    #pragma unroll
    for (int mb = 0; mb < 8; ++mb) {
        #pragma unroll
        for (int r = 0; r < 4; ++r) {
            int rl = mb * 16 + lg * 4 + r;
            int row = m0 + wm + rl;
            float v[4];
            float mx = -INFINITY;
            #pragma unroll
            for (int nb = 0; nb < 4; ++nb) {
                v[nb] = acc[mb][nb][r] + bg[nb];
                mx = fmaxf(mx, v[nb]);
            }
            if (BF16L) {
                #pragma unroll
                for (int nb = 0; nb < 4; ++nb) {
                    int cl = nb * 16 + lr;
                    int slot_w = (cl >> 3) ^ (rl & 7);
                    stile[rl * 64 + slot_w * 8 + (cl & 7)] = f2bf(v[nb]);
                }
            } else {
                float* outp = (float*)logits;
                #pragma unroll
                for (int nb = 0; nb < 4; ++nb)
                    outp[(size_t)row * VOC + n0 + wn + nb * 16 + lr] = v[nb];
            }
            for (int k = 8; k >= 1; k >>= 1) mx = fmaxf(mx, __shfl_xor(mx, k, 16));
            float se = 0.f;
            #pragma unroll
            for (int nb = 0; nb < 4; ++nb) se += __expf(v[nb] - mx);
            for (int k = 8; k >= 1; k >>= 1) se += __shfl_xor(se, k, 16);
            if (lr == 0) {
                float2 pv; pv.x = mx; pv.y = se;
                *(float2*)(partials + ((size_t)row * 500 + chunk) * 2) = pv;
            }
        }
    }
    if (BF16L) {
        ushort* Lbf = (ushort*)logits;
        #pragma unroll
        for (int rep = 0; rep < 16; ++rep) {
            int idx = rep * 64 + lane;
            int rl = idx >> 3, c8 = idx & 7;
            int slot_r = c8 ^ (rl & 7);
            short8 val = *(const short8*)(stile + rl * 64 + slot_r * 8);
            ushort* dst = Lbf + (size_t)(m0 + wm + rl) * VOC + n0 + wn + c8 * 8;
            *(short8*)dst = val;
        }
    }
}

// ---------------- combine per-chunk partials ----------------------------------------
__global__ __launch_bounds__(256) void reduce_kernel(const float* __restrict__ partials,
                                                     float* __restrict__ Ms,
                                                     float* __restrict__ Ss) {
    int wid = threadIdx.x >> 6, lane = threadIdx.x & 63;
    int row = blockIdx.x * 4 + wid;
    float m = -INFINITY, s = 0.f;
    for (int c = lane; c < 500; c += 64) {
        float2 p = *(const float2*)(partials + ((size_t)row * 500 + c) * 2);
        float nm = fmaxf(m, p.x);
        s = s * __expf(m - nm) + p.y * __expf(p.x - nm);
        m = nm;
    }
    for (int k = 32; k >= 1; k >>= 1) {
        float om = __shfl_xor(m, k, 64), os = __shfl_xor(s, k, 64);
        float nm = fmaxf(m, om);
        s = s * __expf(m - nm) + os * __expf(om - nm);
        m = nm;
    }
    if (lane == 0) { Ms[row] = m; Ss[row] = s; }
}

// ---------------- finalize: softmax scale, scatter-add p_c, log ---------------------
template <bool BF16L>
__global__ __launch_bounds__(256) void finalize_kernel(const int* __restrict__ src,
                                                       const float* __restrict__ p_c,
                                                       const float* __restrict__ cp,
                                                       const float* __restrict__ Ms,
                                                       const float* __restrict__ Ss,
                                                       const void* __restrict__ logits,
                                                       float* __restrict__ out) {
    int row = blockIdx.y;
    int c0 = blockIdx.x * 4096;
    int b = row & (BSZ - 1);
    __shared__ float addv[4096];
    int tid = threadIdx.x;
    for (int i = tid; i < 4096; i += 256) addv[i] = 0.f;
    __syncthreads();
    if (tid < SLEN) {
        int v = src[b * SLEN + tid];
        if (v >= c0 && v < c0 + 4096)
            atomicAdd(&addv[swz12(v - c0)], p_c[row * SLEN + tid]);
    }
    __syncthreads();
    int col = c0 + tid * 16;
    if (col >= VOC) return;
    float M = Ms[row];
    float g = (1.f - cp[row]) / Ss[row];
    float L[16];
    if (BF16L) {
        const ushort* lb = (const ushort*)logits + (size_t)row * VOC + col;
        short8 a = *(const short8*)lb;
        short8 c = *(const short8*)(lb + 8);
        for (int i = 0; i < 8; ++i) { L[i] = bf2f((ushort)a[i]); L[8 + i] = bf2f((ushort)c[i]); }
    } else {
        const float* lf = (const float*)logits + (size_t)row * VOC + col;
        for (int i = 0; i < 4; ++i) {
            float4 v = *(const float4*)(lf + i * 4);
            L[i * 4 + 0] = v.x; L[i * 4 + 1] = v.y; L[i * 4 + 2] = v.z; L[i * 4 + 3] = v.w;
        }
    }
    float res[16];
    for (int i = 0; i < 16; ++i) {
        float p = __expf(L[i] - M) * g + addv[swz12(tid * 16 + i)];
        res[i] = __logf(p) + C_CONST_F;
    }
    float* op = out + (size_t)row * VOC + col;
    for (int i = 0; i < 4; ++i) {
        float4 v;
        v.x = res[i * 4 + 0]; v.y = res[i * 4 + 1]; v.z = res[i * 4 + 2]; v.w = res[i * 4 + 3];
        *(float4*)(op + i * 4) = v;
    }
}

extern "C" void kernel_launch(void* const* d_in, const int* in_sizes, int n_in,
                              void* d_out, int out_size, void* d_ws, size_t ws_size,
                              hipStream_t stream) {
    const float* hidden  = (const float*)d_in[0];
    const float* context = (const float*)d_in[1];
    const int*   src     = (const int*)d_in[2];
    const float* W_gen   = (const float*)d_in[3];
    const float* b_gen   = (const float*)d_in[4];
    const float* w_copy  = (const float*)d_in[5];
    const float* b_copy  = (const float*)d_in[6];
    float* out = (float*)d_out;
    char* ws = (char*)d_ws;

    float*  cp       = (float*)(ws);                    // 8 KB
    float*  p_c      = (float*)(ws + 8192);             // 512 KB
    float*  Ms       = (float*)(ws + 532480);
    float*  Ss       = (float*)(ws + 540672);
    float*  partials = (float*)(ws + 548864);           // 8.192 MB
    ushort* Abf      = (ushort*)(ws + 8740864);         // 4 MB   (contiguous with Wbf)
    const size_t NEED_BF16 = 209543168;
    ushort* Lbf      = (ushort*)(ws + 78471168);        // 131 MB

    attn_kernel<<<BSZ * 4, 256, 0, stream>>>(hidden, context, src, w_copy, b_copy, cp, p_c);
    cvt_kernel<<<(NROW * HS / 4 + VOC * HS / 4) / 256, 256, 0, stream>>>(hidden, W_gen, Abf);

    int ggrid = (NROW / BM) * (VOC / BN);   // 8 * 125 = 1000
    dim3 fgrid(8, NROW);
    const ushort* Wb = (const ushort*)(ws + 12935168);
    if (ws_size >= NEED_BF16) {
        gemm_kernel<true><<<ggrid, 512, 0, stream>>>(Abf, Wb, b_gen, Lbf, partials);
        reduce_kernel<<<NROW / 4, 256, 0, stream>>>(partials, Ms, Ss);
        finalize_kernel<true><<<fgrid, 256, 0, stream>>>(src, p_c, cp, Ms, Ss, Lbf, out);
    } else {
        gemm_kernel<false><<<ggrid, 512, 0, stream>>>(Abf, Wb, b_gen, out, partials);
        reduce_kernel<<<NROW / 4, 256, 0, stream>>>(partials, Ms, Ss);
        finalize_kernel<false><<<fgrid, 256, 0, stream>>>(src, p_c, cp, Ms, Ss, out, out);
    }
}

// Round 10
// 316.269 us; speedup vs baseline: 1.1055x; 1.0575x over previous
//
#include <hip/hip_runtime.h>
#include <hip/hip_bf16.h>
#include <stdint.h>

#define TLEN 64
#define BSZ 32
#define SLEN 64
#define HS 1024
#define VOC 32000
#define NROW (TLEN*BSZ)   // 2048
#define C_CONST_F 0.1712209f

// GEMM geometry: 256x256 tile, 8 waves, 4-slot K-pipeline, BK=32/slot (R3/R7-verified)
#define BM 256
#define BN 256
#define BKT 32
#define NKT (HS/BKT)          // 32 K-tiles
#define SLOT_BYTES 32768      // A 16KB + B 16KB
#define B_REGION 16384        // byte offset of B within slot

typedef __attribute__((ext_vector_type(8))) short short8;
typedef __attribute__((ext_vector_type(4))) float f32x4;

static __device__ __forceinline__ ushort f2bf(float f) {
    uint32_t u = __builtin_bit_cast(uint32_t, f);
    uint32_t r = (u + 0x7fffu + ((u >> 16) & 1u)) >> 16;
    return (ushort)r;
}
static __device__ __forceinline__ float bf2f(ushort u) {
    uint32_t v = ((uint32_t)u) << 16;
    return __builtin_bit_cast(float, v);
}
static __device__ __forceinline__ void async16(const void* g, void* lds) {
    __builtin_amdgcn_global_load_lds(
        (const __attribute__((address_space(1))) void*)g,
        (__attribute__((address_space(3))) void*)lds, 16, 0, 0);
}
static __device__ __forceinline__ int swz12(int e) { return e ^ (((e >> 4) & 15) << 1); }

// ---------------- fused pre-pass: MFMA attn (blocks 0..127) + cvt (rest) ------------
// attn: block (b, tq) computes scores[16 t][64 s] via split-bf16 MFMA, masked softmax,
// p_c = attn * sigmoid(gate). cvt: f32->bf16 for [hidden | W_gen], 1 pair f4/thread.
#define ATTN_BLOCKS 128
#define A_PAIRS 262144        // hidden pairs-of-float4 (2048*1024/8)

__global__ __launch_bounds__(256) void pre_kernel(const float* __restrict__ hidden,
                                                  const float* __restrict__ context,
                                                  const int* __restrict__ src,
                                                  const float* __restrict__ w_copy,
                                                  const float* __restrict__ b_copy,
                                                  const float* __restrict__ W_gen,
                                                  float* __restrict__ cp,
                                                  float* __restrict__ p_c,
                                                  ushort* __restrict__ dst) {
    __shared__ float hb[3][16][36];
    __shared__ float cb[3][64][36];
    __shared__ float wb[3][32];
    __shared__ float sc[16][65];
    __shared__ float gred[16];
    __shared__ float cps[16];
    __shared__ int   sbuf[SLEN];

    int tid = threadIdx.x;
    if (blockIdx.x >= ATTN_BLOCKS) {
        // ---- cvt path: 2 float4 -> 1 short8 per thread ----
        int p = (blockIdx.x - ATTN_BLOCKS) * 256 + tid;
        const float* sp = (p < A_PAIRS) ? (hidden + (size_t)p * 8)
                                        : (W_gen + (size_t)(p - A_PAIRS) * 8);
        float4 v0 = *(const float4*)sp;
        float4 v1 = *(const float4*)(sp + 4);
        short8 o;
        o[0] = (short)f2bf(v0.x); o[1] = (short)f2bf(v0.y);
        o[2] = (short)f2bf(v0.z); o[3] = (short)f2bf(v0.w);
        o[4] = (short)f2bf(v1.x); o[5] = (short)f2bf(v1.y);
        o[6] = (short)f2bf(v1.z); o[7] = (short)f2bf(v1.w);
        *(short8*)(dst + (size_t)p * 8) = o;
        return;
    }

    // ---- attn path (R8/R9-verified body) ----
    int b  = blockIdx.x >> 2;
    int tq = blockIdx.x & 3;
    int wid = tid >> 6, lane = tid & 63;
    int lr = lane & 15, lg = lane >> 4;

    if (tid < SLEN) sbuf[tid] = src[b * SLEN + tid];

    const int cidx0 = tid * 2;
    const int cs0 = cidx0 >> 3, ck0 = cidx0 & 7;
    const int cs1 = (cidx0 + 1) >> 3, ck1 = (cidx0 + 1) & 7;
    const float* cbase = context + (size_t)b * HS;
    const float* hbase = hidden + ((size_t)(tq * 16) * 32 + b) * HS;

    float4 rc0, rc1, rh, rw;
#define ALOAD(I)                                                                   \
    {                                                                              \
        rc0 = *(const float4*)(cbase + (size_t)cs0 * 32 * HS + (I) * 32 + ck0 * 4);\
        rc1 = *(const float4*)(cbase + (size_t)cs1 * 32 * HS + (I) * 32 + ck1 * 4);\
        if (tid < 128) rh = *(const float4*)(hbase + (size_t)(tid >> 3) * 32 * HS + (I) * 32 + (tid & 7) * 4); \
        if (tid < 8)  rw = *(const float4*)(w_copy + (I) * 32 + tid * 4);          \
    }
#define AWRITE(BUF)                                                                \
    {                                                                              \
        *(float4*)(&cb[BUF][cs0][ck0 * 4]) = rc0;                                  \
        *(float4*)(&cb[BUF][cs1][ck1 * 4]) = rc1;                                  \
        if (tid < 128) *(float4*)(&hb[BUF][tid >> 3][(tid & 7) * 4]) = rh;         \
        if (tid < 8)  *(float4*)(&wb[BUF][tid * 4]) = rw;                          \
    }

    f32x4 acc = f32x4{0.f, 0.f, 0.f, 0.f};
    float greg = 0.f;
    int gt = lane >> 2, gk = lane & 3;

    ALOAD(0); AWRITE(0);
    ALOAD(1); AWRITE(1);
    ALOAD(2);
    __syncthreads();

    for (int i = 0; i < 32; ++i) {
        int buf = i % 3;
        float4 a0 = *(const float4*)(&hb[buf][lr][lg * 8]);
        float4 a1 = *(const float4*)(&hb[buf][lr][lg * 8 + 4]);
        float4 b0 = *(const float4*)(&cb[buf][wid * 16 + lr][lg * 8]);
        float4 b1 = *(const float4*)(&cb[buf][wid * 16 + lr][lg * 8 + 4]);
        short8 ahi, alo, bhi, blo;
        float af[8] = {a0.x, a0.y, a0.z, a0.w, a1.x, a1.y, a1.z, a1.w};
        float bf[8] = {b0.x, b0.y, b0.z, b0.w, b1.x, b1.y, b1.z, b1.w};
        #pragma unroll
        for (int e = 0; e < 8; ++e) {
            uint32_t ua = __builtin_bit_cast(uint32_t, af[e]);
            ahi[e] = (short)(ua >> 16);
            alo[e] = (short)f2bf(af[e] - __builtin_bit_cast(float, ua & 0xffff0000u));
            uint32_t ub = __builtin_bit_cast(uint32_t, bf[e]);
            bhi[e] = (short)(ub >> 16);
            blo[e] = (short)f2bf(bf[e] - __builtin_bit_cast(float, ub & 0xffff0000u));
        }
        acc = __builtin_amdgcn_mfma_f32_16x16x32_bf16(ahi, bhi, acc, 0, 0, 0);
        acc = __builtin_amdgcn_mfma_f32_16x16x32_bf16(ahi, blo, acc, 0, 0, 0);
        acc = __builtin_amdgcn_mfma_f32_16x16x32_bf16(alo, bhi, acc, 0, 0, 0);
        if (wid == 0) {
            #pragma unroll
            for (int e = 0; e < 8; ++e)
                greg += hb[buf][gt][gk * 8 + e] * wb[buf][gk * 8 + e];
        }
        if (i + 2 < 32) {
            AWRITE((i + 2) % 3);
            if (i + 3 < 32) ALOAD(i + 3);
        }
        __syncthreads();
    }
#undef ALOAD
#undef AWRITE

    if (wid == 0) {
        greg += __shfl_xor(greg, 1, 64);
        greg += __shfl_xor(greg, 2, 64);
        if (gk == 0) gred[gt] = greg;
    }
    #pragma unroll
    for (int r = 0; r < 4; ++r)
        sc[lg * 4 + r][wid * 16 + lr] = acc[r];
    __syncthreads();
    if (tid < 16) {
        float s = 1.f / (1.f + expf(-(gred[tid] + b_copy[0])));
        cps[tid] = s;
        cp[(size_t)(tq * 16 + tid) * 32 + b] = s;
    }
    __syncthreads();
    {
        int t = tid >> 4, e = tid & 15;
        float v[4];
        float mx = -INFINITY;
        #pragma unroll
        for (int i = 0; i < 4; ++i) {
            v[i] = sc[t][e * 4 + i];
            if (sbuf[e * 4 + i] == 0) v[i] = -INFINITY;
            mx = fmaxf(mx, v[i]);
        }
        for (int k = 8; k >= 1; k >>= 1) mx = fmaxf(mx, __shfl_xor(mx, k, 16));
        float se = 0.f;
        #pragma unroll
        for (int i = 0; i < 4; ++i) { v[i] = __expf(v[i] - mx); se += v[i]; }
        for (int k = 8; k >= 1; k >>= 1) se += __shfl_xor(se, k, 16);
        float g = cps[t] / se;
        int row = (tq * 16 + t) * 32 + b;
        float4 o; o.x = v[0] * g; o.y = v[1] * g; o.z = v[2] * g; o.w = v[3] * g;
        *(float4*)(p_c + (size_t)row * SLEN + e * 4) = o;
    }
}

// ---------------- main GEMM (R7-verified, unchanged) --------------------------------
template <bool BF16L>
__global__ __launch_bounds__(512, 2) void gemm_kernel(const ushort* __restrict__ A,
                                                      const ushort* __restrict__ B,
                                                      const float* __restrict__ b_gen,
                                                      void* __restrict__ logits,
                                                      float* __restrict__ partials /*[NROW][500][2]*/) {
    __shared__ ushort sAB[4 * SLOT_BYTES / 2];    // 128 KB, 4 slots

    int orig = blockIdx.x;
    int wg = (orig & 7) * 125 + (orig >> 3);
    int mIdx = wg & 7;            // 8 m-tiles
    int nIdx = wg >> 3;           // 125 n-tiles
    int m0 = mIdx * BM, n0 = nIdx * BN;
    int tid = threadIdx.x, wid = tid >> 6, lane = tid & 63;
    int wm = (wid >> 2) * 128, wn = (wid & 3) * 64;
    int lr = lane & 15, lg = lane >> 4;

    const ushort* gA[2]; const ushort* gB[2];
    uint32_t ldsOffA[2], ldsOffB[2];
    #pragma unroll
    for (int j = 0; j < 2; ++j) {
        int s = j * 512 + tid;
        int row = s >> 2;
        int kc = (s & 3) ^ ((row >> 1) & 3);
        gA[j] = A + (size_t)(m0 + row) * HS + kc * 8;
        gB[j] = B + (size_t)(n0 + row) * HS + kc * 8;
        ldsOffA[j] = (uint32_t)((j * 512 + wid * 64) * 16);
        ldsOffB[j] = (uint32_t)(B_REGION + (j * 512 + wid * 64) * 16);
    }

    uint32_t kcs   = (uint32_t)((lg ^ ((lr >> 1) & 3)) * 16);
    uint32_t offAb = (uint32_t)(wm + lr) * 64 + kcs;
    uint32_t offBb = B_REGION + (uint32_t)(wn + lr) * 64 + kcs;

    f32x4 acc[8][4];
    #pragma unroll
    for (int m = 0; m < 8; ++m)
        #pragma unroll
        for (int n = 0; n < 4; ++n) acc[m][n] = f32x4{0.f, 0.f, 0.f, 0.f};

#define STAGE(KT)                                                          \
    {                                                                      \
        char* sd = (char*)sAB + ((KT) & 3) * SLOT_BYTES;                   \
        int k0s = (KT) * BKT;                                              \
        _Pragma("unroll")                                                  \
        for (int j = 0; j < 2; ++j) {                                      \
            async16(gA[j] + k0s, sd + ldsOffA[j]);                         \
            async16(gB[j] + k0s, sd + ldsOffB[j]);                         \
        }                                                                  \
    }

#define PHASE_BODY(KT, DOSTAGE)                                                        \
    {                                                                                  \
        const char* sl = (const char*)sAB + ((KT) & 3) * SLOT_BYTES;                   \
        short8 af[8], bv[4];                                                           \
        _Pragma("unroll")                                                              \
        for (int mb = 0; mb < 8; ++mb)                                                 \
            af[mb] = *(const short8*)(sl + offAb + mb * 1024);                         \
        _Pragma("unroll")                                                              \
        for (int nb = 0; nb < 4; ++nb)                                                 \
            bv[nb] = *(const short8*)(sl + offBb + nb * 1024);                         \
        if (DOSTAGE) STAGE((KT) + 3);                                                  \
        _Pragma("unroll")                                                              \
        for (int mb = 0; mb < 8; ++mb)                                                 \
            _Pragma("unroll")                                                          \
            for (int nb = 0; nb < 4; ++nb)                                             \
                acc[mb][nb] = __builtin_amdgcn_mfma_f32_16x16x32_bf16(af[mb], bv[nb],  \
                                                                     acc[mb][nb], 0, 0, 0); \
    }

#define GATE8 asm volatile("s_waitcnt vmcnt(8)\n\ts_barrier" ::: "memory")

    STAGE(0); STAGE(1); STAGE(2);

    for (int kb = 0; kb < 7; ++kb) {
        int kt = kb * 4;
        GATE8; PHASE_BODY(kt + 0, true);
        GATE8; PHASE_BODY(kt + 1, true);
        GATE8; PHASE_BODY(kt + 2, true);
        GATE8; PHASE_BODY(kt + 3, true);
    }
    GATE8; PHASE_BODY(28, true);
    GATE8; PHASE_BODY(29, false);
    asm volatile("s_waitcnt vmcnt(4)\n\ts_barrier" ::: "memory");
    PHASE_BODY(30, false);
    asm volatile("s_waitcnt vmcnt(0)\n\ts_barrier" ::: "memory");
    PHASE_BODY(31, false);
#undef PHASE_BODY
#undef STAGE
#undef GATE8

    asm volatile("s_barrier" ::: "memory");

    float bg[4];
    #pragma unroll
    for (int nb = 0; nb < 4; ++nb) bg[nb] = b_gen[n0 + wn + nb * 16 + lr];
    int chunk = nIdx * 4 + (wid & 3);
    ushort* stile = sAB + wid * 8192;

    #pragma unroll
    for (int mb = 0; mb < 8; ++mb) {
        #pragma unroll
        for (int r = 0; r < 4; ++r) {
            int rl = mb * 16 + lg * 4 + r;
            int row = m0 + wm + rl;
            float v[4];
            float mx = -INFINITY;
            #pragma unroll
            for (int nb = 0; nb < 4; ++nb) {
                v[nb] = acc[mb][nb][r] + bg[nb];
                mx = fmaxf(mx, v[nb]);
            }
            if (BF16L) {
                #pragma unroll
                for (int nb = 0; nb < 4; ++nb) {
                    int cl = nb * 16 + lr;
                    int slot_w = (cl >> 3) ^ (rl & 7);
                    stile[rl * 64 + slot_w * 8 + (cl & 7)] = f2bf(v[nb]);
                }
            } else {
                float* outp = (float*)logits;
                #pragma unroll
                for (int nb = 0; nb < 4; ++nb)
                    outp[(size_t)row * VOC + n0 + wn + nb * 16 + lr] = v[nb];
            }
            for (int k = 8; k >= 1; k >>= 1) mx = fmaxf(mx, __shfl_xor(mx, k, 16));
            float se = 0.f;
            #pragma unroll
            for (int nb = 0; nb < 4; ++nb) se += __expf(v[nb] - mx);
            for (int k = 8; k >= 1; k >>= 1) se += __shfl_xor(se, k, 16);
            if (lr == 0) {
                float2 pv; pv.x = mx; pv.y = se;
                *(float2*)(partials + ((size_t)row * 500 + chunk) * 2) = pv;
            }
        }
    }
    if (BF16L) {
        ushort* Lbf = (ushort*)logits;
        #pragma unroll
        for (int rep = 0; rep < 16; ++rep) {
            int idx = rep * 64 + lane;
            int rl = idx >> 3, c8 = idx & 7;
            int slot_r = c8 ^ (rl & 7);
            short8 val = *(const short8*)(stile + rl * 64 + slot_r * 8);
            ushort* dst = Lbf + (size_t)(m0 + wm + rl) * VOC + n0 + wn + c8 * 8;
            *(short8*)dst = val;
        }
    }
}

// ---------------- combine per-chunk partials ----------------------------------------
__global__ __launch_bounds__(256) void reduce_kernel(const float* __restrict__ partials,
                                                     float* __restrict__ Ms,
                                                     float* __restrict__ Ss) {
    int wid = threadIdx.x >> 6, lane = threadIdx.x & 63;
    int row = blockIdx.x * 4 + wid;
    float m = -INFINITY, s = 0.f;
    for (int c = lane; c < 500; c += 64) {
        float2 p = *(const float2*)(partials + ((size_t)row * 500 + c) * 2);
        float nm = fmaxf(m, p.x);
        s = s * __expf(m - nm) + p.y * __expf(p.x - nm);
        m = nm;
    }
    for (int k = 32; k >= 1; k >>= 1) {
        float om = __shfl_xor(m, k, 64), os = __shfl_xor(s, k, 64);
        float nm = fmaxf(m, om);
        s = s * __expf(m - nm) + os * __expf(om - nm);
        m = nm;
    }
    if (lane == 0) { Ms[row] = m; Ss[row] = s; }
}

// ---------------- finalize: softmax scale, scatter-add p_c, log ---------------------
template <bool BF16L>
__global__ __launch_bounds__(256) void finalize_kernel(const int* __restrict__ src,
                                                       const float* __restrict__ p_c,
                                                       const float* __restrict__ cp,
                                                       const float* __restrict__ Ms,
                                                       const float* __restrict__ Ss,
                                                       const void* __restrict__ logits,
                                                       float* __restrict__ out) {
    int row = blockIdx.y;
    int c0 = blockIdx.x * 4096;
    int b = row & (BSZ - 1);
    __shared__ float addv[4096];
    int tid = threadIdx.x;
    for (int i = tid; i < 4096; i += 256) addv[i] = 0.f;
    __syncthreads();
    if (tid < SLEN) {
        int v = src[b * SLEN + tid];
        if (v >= c0 && v < c0 + 4096)
            atomicAdd(&addv[swz12(v - c0)], p_c[row * SLEN + tid]);
    }
    __syncthreads();
    int col = c0 + tid * 16;
    if (col >= VOC) return;
    float M = Ms[row];
    float g = (1.f - cp[row]) / Ss[row];
    float L[16];
    if (BF16L) {
        const ushort* lb = (const ushort*)logits + (size_t)row * VOC + col;
        short8 a = *(const short8*)lb;
        short8 c = *(const short8*)(lb + 8);
        for (int i = 0; i < 8; ++i) { L[i] = bf2f((ushort)a[i]); L[8 + i] = bf2f((ushort)c[i]); }
    } else {
        const float* lf = (const float*)logits + (size_t)row * VOC + col;
        for (int i = 0; i < 4; ++i) {
            float4 v = *(const float4*)(lf + i * 4);
            L[i * 4 + 0] = v.x; L[i * 4 + 1] = v.y; L[i * 4 + 2] = v.z; L[i * 4 + 3] = v.w;
        }
    }
    float res[16];
    for (int i = 0; i < 16; ++i) {
        float p = __expf(L[i] - M) * g + addv[swz12(tid * 16 + i)];
        res[i] = __logf(p) + C_CONST_F;
    }
    float* op = out + (size_t)row * VOC + col;
    for (int i = 0; i < 4; ++i) {
        float4 v;
        v.x = res[i * 4 + 0]; v.y = res[i * 4 + 1]; v.z = res[i * 4 + 2]; v.w = res[i * 4 + 3];
        *(float4*)(op + i * 4) = v;
    }
}

extern "C" void kernel_launch(void* const* d_in, const int* in_sizes, int n_in,
                              void* d_out, int out_size, void* d_ws, size_t ws_size,
                              hipStream_t stream) {
    const float* hidden  = (const float*)d_in[0];
    const float* context = (const float*)d_in[1];
    const int*   src     = (const int*)d_in[2];
    const float* W_gen   = (const float*)d_in[3];
    const float* b_gen   = (const float*)d_in[4];
    const float* w_copy  = (const float*)d_in[5];
    const float* b_copy  = (const float*)d_in[6];
    float* out = (float*)d_out;
    char* ws = (char*)d_ws;

    float*  cp       = (float*)(ws);                    // 8 KB
    float*  p_c      = (float*)(ws + 8192);             // 512 KB
    float*  Ms       = (float*)(ws + 532480);
    float*  Ss       = (float*)(ws + 540672);
    float*  partials = (float*)(ws + 548864);           // 8.192 MB
    ushort* Abf      = (ushort*)(ws + 8740864);         // 4 MB   (contiguous with Wbf)
    const size_t NEED_BF16 = 209543168;
    ushort* Lbf      = (ushort*)(ws + 78471168);        // 131 MB

    // pre: 128 attn blocks + 17024 cvt blocks (2 float4-pairs per thread)
    int preGrid = ATTN_BLOCKS + (NROW * HS + VOC * HS) / 8 / 256;
    pre_kernel<<<preGrid, 256, 0, stream>>>(hidden, context, src, w_copy, b_copy,
                                            W_gen, cp, p_c, Abf);

    int ggrid = (NROW / BM) * (VOC / BN);   // 8 * 125 = 1000
    dim3 fgrid(8, NROW);
    const ushort* Wb = (const ushort*)(ws + 12935168);
    if (ws_size >= NEED_BF16) {
        gemm_kernel<true><<<ggrid, 512, 0, stream>>>(Abf, Wb, b_gen, Lbf, partials);
        reduce_kernel<<<NROW / 4, 256, 0, stream>>>(partials, Ms, Ss);
        finalize_kernel<true><<<fgrid, 256, 0, stream>>>(src, p_c, cp, Ms, Ss, Lbf, out);
    } else {
        gemm_kernel<false><<<ggrid, 512, 0, stream>>>(Abf, Wb, b_gen, out, partials);
        reduce_kernel<<<NROW / 4, 256, 0, stream>>>(partials, Ms, Ss);
        finalize_kernel<false><<<fgrid, 256, 0, stream>>>(src, p_c, cp, Ms, Ss, out, out);
    }
}